// Round 8
// baseline (179.545 us; speedup 1.0000x reference)
//
#include <hip/hip_runtime.h>

#define NS 4096
#define NCC 1024
#define DD 64
#define HH2 32
#define NSEQ 32
#define SLEN 256
#define SLOTS 8192
#define LNEPS 1e-3f
#define MAXSPS 1024   // max sites per sequence (mean 128 — huge margin)

// ---------------- K_setup: blocks 0-19 = prep (256 rows each), blocks 20-21 = counting sort ----------------
__global__ void __launch_bounds__(1024) k_setup(
    const float* __restrict__ sites, const float* __restrict__ cons,
    const float* __restrict__ Ws, const float* __restrict__ bs,
    const float* __restrict__ Wc, const float* __restrict__ bc,
    const float* __restrict__ Wd, const float* __restrict__ bd,
    const float* __restrict__ g, const float* __restrict__ Wo,
    float* __restrict__ u, float* __restrict__ A, float* __restrict__ P,
    float* __restrict__ v, float* __restrict__ B, float* __restrict__ Q,
    const int* __restrict__ idxl, const int* __restrict__ idxh,
    int* __restrict__ offl, int* __restrict__ slotl, int* __restrict__ sitel,
    int* __restrict__ offh, int* __restrict__ sloth, int* __restrict__ siteh) {
  __shared__ int cnt[SLOTS];
  __shared__ int wsumI[16];
  int tid = threadIdx.x;
  if (blockIdx.x < 20) {
    // ---- prep: 4 waves/block, one row per thread ----
    if (tid >= 256) return;
    int t = blockIdx.x * 256 + tid;
    if (t >= NS + NCC) return;
    bool isSite = t < NS;
    int row = isSite ? t : t - NS;
    const float* x = isSite ? sites + row * DD : cons + row * DD;
    const float* W1 = isSite ? Ws : Wc;
    const float* b1 = isSite ? bs : bc;
    float s[HH2];
#pragma unroll
    for (int h = 0; h < HH2; h++) s[h] = b1[h];
    for (int k = 0; k < DD; k++) {
      float xv = x[k];
#pragma unroll
      for (int h = 0; h < HH2; h++) s[h] = fmaf(xv, W1[k * HH2 + h], s[h]);
    }
#pragma unroll
    for (int h = 0; h < HH2; h++) s[h] = fmaxf(s[h], 0.0f);
    float hs[HH2];
#pragma unroll
    for (int h = 0; h < HH2; h++) hs[h] = isSite ? 0.0f : bd[h];  // b_d folded into con side
    for (int k = 0; k < HH2; k++) {
      float sv = s[k];
#pragma unroll
      for (int h = 0; h < HH2; h++) hs[h] = fmaf(sv, Wd[k * HH2 + h], hs[h]);
    }
    float mu = 0.f;
#pragma unroll
    for (int h = 0; h < HH2; h++) mu += hs[h];
    mu *= (1.0f / HH2);
    float p = 0.f, a = 0.f;
    float* dst = isSite ? (u + row * HH2) : (v + row * HH2);
#pragma unroll
    for (int h = 0; h < HH2; h++) {
      float uu = hs[h] - mu;
      dst[h] = uu;
      p += uu * uu;
      a = fmaf(uu * g[h], Wo[h], a);
    }
    p *= (1.0f / HH2);
    if (isSite) { A[row] = a; P[row] = p; } else { B[row] = a; Q[row] = p; }
    return;
  }
  // ---- sort (blocks 20,21) ----
  int lane = tid & 63, wv = tid >> 6;
  int pass = blockIdx.x - 20;
  const int* idx = pass ? idxh : idxl;
  int* off = pass ? offh : offl;
  int* slotA = pass ? sloth : slotl;
  int* siteA = pass ? siteh : sitel;
  for (int i2 = tid; i2 < SLOTS; i2 += 1024) cnt[i2] = 0;
  __syncthreads();
  for (int i2 = tid; i2 < NS; i2 += 1024) atomicAdd(&cnt[idx[i2]], 1);
  __syncthreads();
  int base = tid * 8;
  int loc[8]; int sum = 0;
#pragma unroll
  for (int q2 = 0; q2 < 8; q2++) { loc[q2] = sum; sum += cnt[base + q2]; }
  int incl = sum;
#pragma unroll
  for (int o = 1; o < 64; o <<= 1) { int t2 = __shfl_up(incl, o); if (lane >= o) incl += t2; }
  if (lane == 63) wsumI[wv] = incl;
  __syncthreads();
  int wprev = 0;
#pragma unroll
  for (int w = 0; w < 16; w++) { int t3 = wsumI[w]; if (w < wv) wprev += t3; }
  int excl = wprev + (incl - sum);
  __syncthreads();
#pragma unroll
  for (int q2 = 0; q2 < 8; q2++) { int o2 = excl + loc[q2]; off[base + q2] = o2; cnt[base + q2] = o2; }
  if (tid == 0) off[SLOTS] = NS;
  __syncthreads();
  for (int i2 = tid; i2 < NS; i2 += 1024) {
    int sl = idx[i2];
    int pos = atomicAdd(&cnt[sl], 1);
    slotA[pos] = sl; siteA[pos] = i2;
  }
}

// ---------------- K_main: logits -> softmax -> forward cumsum; 16 rows/block, 1 barrier ----------------
// Only M and CH are materialized; CL is recovered in k_bandL as 1 - CH + M.
__global__ void __launch_bounds__(1024) k_main(const float* __restrict__ u,
    const float* __restrict__ A, const float* __restrict__ P,
    const float* __restrict__ v, const float* __restrict__ B, const float* __restrict__ Q,
    const float* __restrict__ lnb, const float* __restrict__ Wo, const float* __restrict__ bo,
    float* __restrict__ M, float* __restrict__ CHp) {
  int j = threadIdx.x;
  int lane = j & 63, wv = j >> 6;
  __shared__ float redB[16 * 16];  // [row][wave] wave sums
  float4 vv[8];
  const float4* vp = (const float4*)(v + j * HH2);
#pragma unroll
  for (int q = 0; q < 8; q++) vv[q] = vp[q];
  float Bj = B[j], Qj = Q[j];
  float C = bo[0];
#pragma unroll
  for (int k = 0; k < HH2; k++) C = fmaf(lnb[k], Wo[k], C);
  int row0 = blockIdx.x * 16;

  float e[16], incl[16];
#pragma unroll
  for (int rr = 0; rr < 16; rr++) {
    int i = row0 + rr;
    const float4* up = (const float4*)(u + i * HH2);
    float dot = 0.f;
#pragma unroll
    for (int q = 0; q < 8; q++) {
      float4 u4 = up[q];
      dot = fmaf(u4.x, vv[q].x, dot);
      dot = fmaf(u4.y, vv[q].y, dot);
      dot = fmaf(u4.z, vv[q].z, dot);
      dot = fmaf(u4.w, vv[q].w, dot);
    }
    float var = P[i] + Qj + dot * 0.0625f;   // P + Q + 2*dot/32
    float lg = rsqrtf(var + LNEPS) * (A[i] + Bj) + C;
    float ee = __expf(lg);
    float ic = ee;
#pragma unroll
    for (int o = 1; o < 64; o <<= 1) { float tt = __shfl_up(ic, o); if (lane >= o) ic += tt; }
    if (lane == 63) redB[rr * 16 + wv] = ic;
    e[rr] = ee; incl[rr] = ic;
  }
  __syncthreads();
#pragma unroll
  for (int rr = 0; rr < 16; rr++) {
    const float4* rb = (const float4*)(redB + rr * 16);
    float4 b0 = rb[0], b1 = rb[1], b2 = rb[2], b3 = rb[3];
    float w_[16] = {b0.x, b0.y, b0.z, b0.w, b1.x, b1.y, b1.z, b1.w,
                    b2.x, b2.y, b2.z, b2.w, b3.x, b3.y, b3.z, b3.w};
    float prev = 0.f, tot = 0.f;
#pragma unroll
    for (int w = 0; w < 16; w++) { tot += w_[w]; if (w < wv) prev += w_[w]; }
    float chE = prev + incl[rr];
    float rd = 1.0f / tot;
    int o_ = (row0 + rr) * NCC + j;
    M[o_] = e[rr] * rd;                    // softmax (to d_out)
    CHp[o_] = chE * rd;                    // forward cumsum
  }
}

// ---------------- K_bandL: lower band from CH,M (cv = 1 - ch + m); writes EL; T=12 ----------------
// grid = (8 coltiles, 32 seqs), block = 64 threads x 2 cols (float2)
__global__ void __launch_bounds__(64, 1) k_bandL(const float* __restrict__ CHp,
    const float* __restrict__ Mp,
    const int* __restrict__ offl, const int* __restrict__ slotl, const int* __restrict__ sitel,
    float* __restrict__ EL) {
  int seq = blockIdx.y;
  int j0 = blockIdx.x * 128 + threadIdx.x * 2;
  int s0 = offl[seq * SLEN];
  int s1 = offl[seq * SLEN + SLEN];
  int n = s1 - s0;
  __shared__ int ss[MAXSPS];
  __shared__ int sl[MAXSPS];
  for (int i = threadIdx.x; i < n; i += 64) { ss[i] = sitel[s0 + i]; sl[i] = slotl[s0 + i]; }
  __syncthreads();
  if (n <= 0) return;

  const int T = 12;
  float2 cA[T], cB[T], mA[T], mB[T];
#pragma unroll
  for (int k = 0; k < T; k++) {
    int kk = k < n ? k : n - 1;
    size_t base = (size_t)ss[kk] * NCC + j0;
    cA[k] = *(const float2*)(CHp + base);
    mA[k] = *(const float2*)(Mp + base);
  }
#pragma unroll
  for (int k = 0; k < T; k++) {
    int kk = T + k < n ? T + k : n - 1;
    size_t base = (size_t)ss[kk] * NCC + j0;
    cB[k] = *(const float2*)(CHp + base);
    mB[k] = *(const float2*)(Mp + base);
  }
  float2 r = make_float2(1.f, 1.f);
  float2 z = make_float2(0.f, 0.f);
  int prev = -1;
  int ntiles = (n + T - 1) / T;
  for (int t = 0; t < ntiles; t += 2) {
#pragma unroll
    for (int k = 0; k < T; k++) {
      int cur = t * T + k;
      if (cur < n) {
        float2 ch = cA[k], m = mA[k];
        float2 cv = make_float2(1.f - ch.x + m.x, 1.f - ch.y + m.y);
        int slot = sl[cur];
        if (slot != prev) {
          if (prev >= 0) {
            r.x *= fmaxf(1.f - z.x, 0.f);
            r.y *= fmaxf(1.f - z.y, 0.f);
            z = make_float2(0.f, 0.f);
          }
          prev = slot;
        }
        *(float2*)(EL + (size_t)ss[cur] * NCC + j0) = r;
        z.x += cv.x; z.y += cv.y;
      }
    }
#pragma unroll
    for (int k = 0; k < T; k++) {
      int idx2 = (t + 2) * T + k;
      int kk = idx2 < n ? idx2 : n - 1;
      size_t base = (size_t)ss[kk] * NCC + j0;
      cA[k] = *(const float2*)(CHp + base);
      mA[k] = *(const float2*)(Mp + base);
    }
#pragma unroll
    for (int k = 0; k < T; k++) {
      int cur = (t + 1) * T + k;
      if (cur < n) {
        float2 ch = cB[k], m = mB[k];
        float2 cv = make_float2(1.f - ch.x + m.x, 1.f - ch.y + m.y);
        int slot = sl[cur];
        if (slot != prev) {
          if (prev >= 0) {
            r.x *= fmaxf(1.f - z.x, 0.f);
            r.y *= fmaxf(1.f - z.y, 0.f);
            z = make_float2(0.f, 0.f);
          }
          prev = slot;
        }
        *(float2*)(EL + (size_t)ss[cur] * NCC + j0) = r;
        z.x += cv.x; z.y += cv.y;
      }
    }
#pragma unroll
    for (int k = 0; k < T; k++) {
      int idx2 = (t + 3) * T + k;
      int kk = idx2 < n ? idx2 : n - 1;
      size_t base = (size_t)ss[kk] * NCC + j0;
      cB[k] = *(const float2*)(CHp + base);
      mB[k] = *(const float2*)(Mp + base);
    }
  }
}

// ---------------- K_bandH: higher band fused with final: out = M * EL * r; T=12 ----------------
__global__ void __launch_bounds__(64, 1) k_bandH(const float* __restrict__ CHp,
    const int* __restrict__ offh, const int* __restrict__ sloth, const int* __restrict__ siteh,
    const float* __restrict__ EL, float* __restrict__ out) {
  int seq = blockIdx.y;
  int j0 = blockIdx.x * 128 + threadIdx.x * 2;
  int s0 = offh[seq * SLEN];
  int s1 = offh[seq * SLEN + SLEN];
  int n = s1 - s0;
  __shared__ int ss[MAXSPS];
  __shared__ int sl[MAXSPS];
  for (int i = threadIdx.x; i < n; i += 64) { ss[i] = siteh[s0 + i]; sl[i] = sloth[s0 + i]; }
  __syncthreads();
  if (n <= 0) return;

  const int T = 12;
  float2 cA[T], cB[T], mA[T], mB[T], eA[T], eB[T];
#pragma unroll
  for (int k = 0; k < T; k++) {
    int kk = k < n ? k : n - 1;
    size_t base = (size_t)ss[kk] * NCC + j0;
    cA[k] = *(const float2*)(CHp + base);
    mA[k] = *(const float2*)(out + base);
    eA[k] = *(const float2*)(EL + base);
  }
#pragma unroll
  for (int k = 0; k < T; k++) {
    int kk = T + k < n ? T + k : n - 1;
    size_t base = (size_t)ss[kk] * NCC + j0;
    cB[k] = *(const float2*)(CHp + base);
    mB[k] = *(const float2*)(out + base);
    eB[k] = *(const float2*)(EL + base);
  }
  float2 r = make_float2(1.f, 1.f);
  float2 z = make_float2(0.f, 0.f);
  int prev = -1;
  int ntiles = (n + T - 1) / T;
  for (int t = 0; t < ntiles; t += 2) {
#pragma unroll
    for (int k = 0; k < T; k++) {
      int cur = t * T + k;
      if (cur < n) {
        float2 cv = cA[k], mv = mA[k], ev = eA[k];
        int slot = sl[cur];
        if (slot != prev) {
          if (prev >= 0) {
            r.x *= fmaxf(1.f - z.x, 0.f);
            r.y *= fmaxf(1.f - z.y, 0.f);
            z = make_float2(0.f, 0.f);
          }
          prev = slot;
        }
        float2 ov;
        ov.x = mv.x * ev.x * r.x;
        ov.y = mv.y * ev.y * r.y;
        *(float2*)(out + (size_t)ss[cur] * NCC + j0) = ov;
        z.x += cv.x; z.y += cv.y;
      }
    }
#pragma unroll
    for (int k = 0; k < T; k++) {
      int idx2 = (t + 2) * T + k;
      int kk = idx2 < n ? idx2 : n - 1;
      size_t base = (size_t)ss[kk] * NCC + j0;
      cA[k] = *(const float2*)(CHp + base);
      mA[k] = *(const float2*)(out + base);
      eA[k] = *(const float2*)(EL + base);
    }
#pragma unroll
    for (int k = 0; k < T; k++) {
      int cur = (t + 1) * T + k;
      if (cur < n) {
        float2 cv = cB[k], mv = mB[k], ev = eB[k];
        int slot = sl[cur];
        if (slot != prev) {
          if (prev >= 0) {
            r.x *= fmaxf(1.f - z.x, 0.f);
            r.y *= fmaxf(1.f - z.y, 0.f);
            z = make_float2(0.f, 0.f);
          }
          prev = slot;
        }
        float2 ov;
        ov.x = mv.x * ev.x * r.x;
        ov.y = mv.y * ev.y * r.y;
        *(float2*)(out + (size_t)ss[cur] * NCC + j0) = ov;
        z.x += cv.x; z.y += cv.y;
      }
    }
#pragma unroll
    for (int k = 0; k < T; k++) {
      int idx2 = (t + 3) * T + k;
      int kk = idx2 < n ? idx2 : n - 1;
      size_t base = (size_t)ss[kk] * NCC + j0;
      cB[k] = *(const float2*)(CHp + base);
      mB[k] = *(const float2*)(out + base);
      eB[k] = *(const float2*)(EL + base);
    }
  }
}

extern "C" void kernel_launch(void* const* d_in, const int* in_sizes, int n_in,
                              void* d_out, int out_size, void* d_ws, size_t ws_size,
                              hipStream_t stream) {
  const float* sites = (const float*)d_in[0];
  const float* cons  = (const float*)d_in[1];
  const int* idxl = (const int*)d_in[2];
  const int* idxh = (const int*)d_in[3];
  const float* Ws = (const float*)d_in[4];
  const float* bs = (const float*)d_in[5];
  const float* Wc = (const float*)d_in[6];
  const float* bc = (const float*)d_in[7];
  const float* Wd = (const float*)d_in[8];
  const float* bd = (const float*)d_in[9];
  const float* lng = (const float*)d_in[10];
  const float* lnb = (const float*)d_in[11];
  const float* Wo = (const float*)d_in[12];
  const float* bo = (const float*)d_in[13];

  char* wsb = (char*)d_ws;
  size_t o = 0;
  auto alloc = [&](size_t bytes) { char* p = wsb + o; o += (bytes + 15) & ~(size_t)15; return p; };
  float* u   = (float*)alloc((size_t)NS * HH2 * 4);
  float* A   = (float*)alloc((size_t)NS * 4);
  float* P   = (float*)alloc((size_t)NS * 4);
  float* v   = (float*)alloc((size_t)NCC * HH2 * 4);
  float* B   = (float*)alloc((size_t)NCC * 4);
  float* Q   = (float*)alloc((size_t)NCC * 4);
  float* CHp = (float*)alloc((size_t)NS * NCC * 4);
  float* EL  = (float*)alloc((size_t)NS * NCC * 4);
  int* offl  = (int*)alloc((SLOTS + 1) * 4);
  int* slotl = (int*)alloc(NS * 4);
  int* sitel = (int*)alloc(NS * 4);
  int* offh  = (int*)alloc((SLOTS + 1) * 4);
  int* sloth = (int*)alloc(NS * 4);
  int* siteh = (int*)alloc(NS * 4);

  k_setup<<<22, 1024, 0, stream>>>(sites, cons, Ws, bs, Wc, bc, Wd, bd, lng, Wo,
                                   u, A, P, v, B, Q,
                                   idxl, idxh, offl, slotl, sitel, offh, sloth, siteh);
  k_main<<<NS / 16, 1024, 0, stream>>>(u, A, P, v, B, Q, lnb, Wo, bo,
                                       (float*)d_out, CHp);
  k_bandL<<<dim3(8, NSEQ), 64, 0, stream>>>(CHp, (const float*)d_out, offl, slotl, sitel, EL);
  k_bandH<<<dim3(8, NSEQ), 64, 0, stream>>>(CHp, offh, sloth, siteh, EL, (float*)d_out);
}